// Round 7
// baseline (451.800 us; speedup 1.0000x reference)
//
#include <hip/hip_runtime.h>

#define NN 50000
#define NE 800000
#define NBUK 196          // ceil(NN/256)
#define EB_BLOCKS 196     // ceil(NE/4096)
#define BCAP 5120         // per-bucket LDS cap; mean 4081, sigma 64 -> +16 sigma

typedef __attribute__((ext_vector_type(8))) _Float16 f16x8;
typedef __attribute__((ext_vector_type(16))) float f32x16;
typedef __attribute__((ext_vector_type(4))) _Float16 half4v;

__device__ inline ushort f2h(float f) {
    _Float16 h = (_Float16)f;  // RNE
    union { _Float16 h; ushort u; } v; v.h = h;
    return v.u;
}
__device__ inline float h2f(ushort u) {
    union { _Float16 h; ushort u; } v; v.u = u;
    return (float)v.h;
}

// async global->LDS, 16B per lane; LDS dest is wave-uniform base + lane*16 (m104)
typedef unsigned int u32_g __attribute__((address_space(1)));
typedef unsigned int u32_l __attribute__((address_space(3)));
__device__ inline void gload16(const ushort* g, ushort* l) {
    __builtin_amdgcn_global_load_lds((const u32_g*)g, (u32_l*)l, 16, 0, 0);
}

// row-group load: 4 contiguous elems at group index idx (fp32: 16B, fp16: 8B)
template <bool F16>
__device__ inline float4 ldrow(const float* __restrict__ H, size_t idx) {
    if (F16) {
        half4v h = ((const half4v*)H)[idx];
        return make_float4((float)h.x, (float)h.y, (float)h.z, (float)h.w);
    } else {
        return ((const float4*)H)[idx];
    }
}

// ---------------- CSR build: write-coalesced 2-level bucket sort ----------------
// Replaces atomic scatter (52us, 51.9MB writes = 800K x 64B write-granule waste)
// with bucket-grouped writes. Also derives row_ptr + dinv in bucket_sort.

__global__ __launch_bounds__(256) void zero_int_kernel(int* __restrict__ p, int n) {
    int i = blockIdx.x * 256 + threadIdx.x;
    if (i < n) p[i] = 0;
}

// per-block LDS histogram of dst>>8 -> 196 global atomics per block
__global__ __launch_bounds__(256) void bucket_hist_kernel(const int* __restrict__ dst,
                                                          int* __restrict__ gcnt) {
    __shared__ int cnt[256];
    int tid = threadIdx.x;
    cnt[tid] = 0;
    __syncthreads();
    int e0 = blockIdx.x * 4096;
#pragma unroll
    for (int i = 0; i < 16; ++i) {
        int e = e0 + i * 256 + tid;
        if (e < NE) atomicAdd(&cnt[dst[e] >> 8], 1);
    }
    __syncthreads();
    if (tid < NBUK && cnt[tid] > 0) atomicAdd(&gcnt[tid], cnt[tid]);
}

// 1-block exclusive scan of bucket counts -> bucket bases (+ phase-A cursors)
__global__ __launch_bounds__(256) void bucket_scan_kernel(const int* __restrict__ gcnt,
                                                          int* __restrict__ bbase,
                                                          int* __restrict__ bcur,
                                                          int* __restrict__ row_ptr) {
    __shared__ int s[256];
    int tid = threadIdx.x;
    int v = (tid < NBUK) ? gcnt[tid] : 0;
    s[tid] = v;
    __syncthreads();
    for (int o = 1; o < 256; o <<= 1) {
        int t = (tid >= o) ? s[tid - o] : 0;
        __syncthreads();
        s[tid] += t;
        __syncthreads();
    }
    int excl = s[tid] - v;
    if (tid < NBUK) { bbase[tid] = excl; bcur[tid] = excl; }
    if (tid == 0) row_ptr[NN] = NE;
}

// Phase A: partition 4096 edges/block into bucket-major intermediate buffer.
// Pack = (src<<8) | (dst&255): src<50000<2^16, so 24 bits fit one u32.
__global__ __launch_bounds__(256) void edge_bin_kernel(const int* __restrict__ src,
                                                       const int* __restrict__ dst,
                                                       int* __restrict__ bcur,
                                                       unsigned* __restrict__ ebuf) {
    __shared__ int cnt[256];
    __shared__ int off[256];
    __shared__ int cur[256];
    __shared__ int gbase[256];
    __shared__ unsigned stage[4096];
    __shared__ unsigned char bmap[4096];
    int tid = threadIdx.x;
    int e0 = blockIdx.x * 4096;
    int filled = min(4096, NE - e0);
    cnt[tid] = 0;
    __syncthreads();
#pragma unroll
    for (int i = 0; i < 16; ++i) {
        int e = e0 + i * 256 + tid;
        if (e < NE) atomicAdd(&cnt[dst[e] >> 8], 1);
    }
    __syncthreads();
    int v = cnt[tid];
    off[tid] = v;
    __syncthreads();
    for (int o = 1; o < 256; o <<= 1) {
        int t = (tid >= o) ? off[tid - o] : 0;
        __syncthreads();
        off[tid] += t;
        __syncthreads();
    }
    int excl = off[tid] - v;
    __syncthreads();
    off[tid] = excl;     // now exclusive
    cur[tid] = excl;
    if (tid < NBUK && v > 0) gbase[tid] = atomicAdd(&bcur[tid], v);
    __syncthreads();
#pragma unroll
    for (int i = 0; i < 16; ++i) {
        int e = e0 + i * 256 + tid;
        if (e < NE) {
            int d = dst[e];
            int b = d >> 8;
            int p = atomicAdd(&cur[b], 1);
            stage[p] = ((unsigned)src[e] << 8) | (unsigned)(d & 255);
            bmap[p] = (unsigned char)b;
        }
    }
    __syncthreads();
    for (int s2 = tid; s2 < filled; s2 += 256) {
        int b = bmap[s2];
        ebuf[gbase[b] + (s2 - off[b])] = stage[s2];
    }
}

// Phase B: one block per bucket (256 nodes). Exact per-node counts -> row_ptr
// segment + dinv; LDS counting-sort; coalesced flush.
__global__ __launch_bounds__(256) void bucket_sort_kernel(const int* __restrict__ bbase,
                                                          const unsigned* __restrict__ ebuf,
                                                          int* __restrict__ col_src,
                                                          int* __restrict__ row_ptr,
                                                          float* __restrict__ dinv) {
    __shared__ int cnt[256];
    __shared__ int off[256];
    __shared__ int cur[256];
    __shared__ unsigned pk[BCAP];
    __shared__ int outv[BCAP];
    int tid = threadIdx.x;
    int nb = blockIdx.x;
    int n0 = nb << 8;
    int base = bbase[nb];
    int cntE = ((nb + 1 < NBUK) ? bbase[nb + 1] : NE) - base;
    cnt[tid] = 0;
    __syncthreads();
    for (int e = tid; e < cntE; e += 256) {
        unsigned p = ebuf[base + e];
        pk[e] = p;
        atomicAdd(&cnt[(int)(p & 255u)], 1);
    }
    __syncthreads();
    int v = cnt[tid];
    off[tid] = v;
    __syncthreads();
    for (int o = 1; o < 256; o <<= 1) {
        int t = (tid >= o) ? off[tid - o] : 0;
        __syncthreads();
        off[tid] += t;
        __syncthreads();
    }
    int excl = off[tid] - v;
    cur[tid] = excl;
    int n = n0 + tid;
    if (n < NN) {
        row_ptr[n] = base + excl;
        dinv[n] = rsqrtf((float)(v + 1));  // +1 self loop
    }
    __syncthreads();
    for (int e = tid; e < cntE; e += 256) {
        unsigned p = pk[e];
        int pos = atomicAdd(&cur[(int)(p & 255u)], 1);
        outv[pos] = (int)(p >> 8);
    }
    __syncthreads();
    for (int e = tid; e < cntE; e += 256) col_src[base + e] = outv[e];
}

// ---- fused weight split+transpose W2..W5: W[K][Nd] fp32 -> [Nd][K] fp16 (single plane) ----

__global__ __launch_bounds__(256) void split_all_kernel(
    const float* __restrict__ W2, const float* __restrict__ W3,
    const float* __restrict__ W4, const float* __restrict__ W5,
    ushort* __restrict__ W2th, ushort* __restrict__ W3th,
    ushort* __restrict__ W4th, ushort* __restrict__ W5th) {
    int i = blockIdx.x * 256 + threadIdx.x;
    const float* W; ushort* Wth; int K, Nd, idx;
    if (i < 16384) {                     // W2: 64x256
        W = W2; Wth = W2th; K = 64; Nd = 256; idx = i;
    } else if (i < 147456) {             // W3: 256x512
        W = W3; Wth = W3th; K = 256; Nd = 512; idx = i - 16384;
    } else if (i < 278528) {             // W4: 512x256
        W = W4; Wth = W4th; K = 512; Nd = 256; idx = i - 147456;
    } else if (i < 294912) {             // W5: 256x64
        W = W5; Wth = W5th; K = 256; Nd = 64; idx = i - 278528;
    } else {
        return;
    }
    int k = idx / Nd, n = idx - k * Nd;
    Wth[(size_t)n * K + k] = f2h(W[idx]);
}

// ------- aggregation: out[v] = dv*sum du*H[u] + dv^2*H[v] (+bias,relu | fp16 out) ----
// vectorized: GS = WD/4 lanes/node, one 4-elem group per lane, 8-deep gather prefetch.
// BW-bound at ~3.7 TB/s on the random-gather fetch path (r0-r4: time scales with
// fetch bytes; r5: column-splitting null-to-negative -> at structural floor).

template <int WD, bool BIAS, bool RELU, bool F16O, bool F16IN>
__global__ __launch_bounds__(256) void aggregate_vec_kernel(
    const float* __restrict__ H, const float* __restrict__ dinv,
    const int* __restrict__ row_ptr, const int* __restrict__ col_src,
    const float* __restrict__ bias, float* __restrict__ out,
    ushort* __restrict__ oh) {
    const int GS = WD / 4;
    const int NPB = 256 / GS;
    int v = blockIdx.x * NPB + (threadIdx.x / GS);
    int lg = threadIdx.x & (GS - 1);
    if (v >= NN) return;
    float dv = dinv[v];
    int beg = row_ptr[v], end = row_ptr[v + 1];
    float4 self = ldrow<F16IN>(H, (size_t)v * GS + lg);
    float4 acc = make_float4(0.f, 0.f, 0.f, 0.f);
    for (int cbeg = beg; cbeg < end; cbeg += GS) {
        int cnt = min(GS, end - cbeg);
        int u_l = (lg < cnt) ? col_src[cbeg + lg] : 0;
        float w_l = (lg < cnt) ? dinv[u_l] : 0.0f;
        int e = 0;
        for (; e + 8 <= cnt; e += 8) {
            int u[8]; float w[8]; float4 h[8];
#pragma unroll
            for (int t = 0; t < 8; ++t) {
                u[t] = __shfl(u_l, e + t, GS);
                w[t] = __shfl(w_l, e + t, GS);
            }
#pragma unroll
            for (int t = 0; t < 8; ++t) h[t] = ldrow<F16IN>(H, (size_t)u[t] * GS + lg);
#pragma unroll
            for (int t = 0; t < 8; ++t) {
                acc.x = fmaf(w[t], h[t].x, acc.x); acc.y = fmaf(w[t], h[t].y, acc.y);
                acc.z = fmaf(w[t], h[t].z, acc.z); acc.w = fmaf(w[t], h[t].w, acc.w);
            }
        }
        for (; e + 4 <= cnt; e += 4) {
            int u[4]; float w[4]; float4 h[4];
#pragma unroll
            for (int t = 0; t < 4; ++t) {
                u[t] = __shfl(u_l, e + t, GS);
                w[t] = __shfl(w_l, e + t, GS);
            }
#pragma unroll
            for (int t = 0; t < 4; ++t) h[t] = ldrow<F16IN>(H, (size_t)u[t] * GS + lg);
#pragma unroll
            for (int t = 0; t < 4; ++t) {
                acc.x = fmaf(w[t], h[t].x, acc.x); acc.y = fmaf(w[t], h[t].y, acc.y);
                acc.z = fmaf(w[t], h[t].z, acc.z); acc.w = fmaf(w[t], h[t].w, acc.w);
            }
        }
        for (; e < cnt; ++e) {
            int u = __shfl(u_l, e, GS);
            float w = __shfl(w_l, e, GS);
            float4 h = ldrow<F16IN>(H, (size_t)u * GS + lg);
            acc.x = fmaf(w, h.x, acc.x); acc.y = fmaf(w, h.y, acc.y);
            acc.z = fmaf(w, h.z, acc.z); acc.w = fmaf(w, h.w, acc.w);
        }
    }
    float dv2 = dv * dv;
    float4 r;
    r.x = fmaf(dv, acc.x, dv2 * self.x);
    r.y = fmaf(dv, acc.y, dv2 * self.y);
    r.z = fmaf(dv, acc.z, dv2 * self.z);
    r.w = fmaf(dv, acc.w, dv2 * self.w);
    if (BIAS) {
        float4 b = ((const float4*)bias)[lg];
        r.x += b.x; r.y += b.y; r.z += b.z; r.w += b.w;
    }
    if (RELU) {
        r.x = fmaxf(r.x, 0.f); r.y = fmaxf(r.y, 0.f);
        r.z = fmaxf(r.z, 0.f); r.w = fmaxf(r.w, 0.f);
    }
    if (F16O) {
        ushort4 hv;
        hv.x = f2h(r.x); hv.y = f2h(r.y); hv.z = f2h(r.z); hv.w = f2h(r.w);
        *(ushort4*)&oh[(size_t)v * WD + lg * 4] = hv;
    } else {
        ((float4*)out)[(size_t)v * GS + lg] = r;
    }
}

// ---------------- f16 MFMA GEMM (32x32x16): C = A @ Wt^T ----------------
// A fp16 exact, W single fp16 plane -> 1 MFMA per fragment pair.
// 128x128 tile, 4 waves 2x2; global_load_lds staging, double-buffered,
// single __syncthreads per K-step.
// STAGING MAP (r7, bank-conflict fix): lane l of each 1KB wave-load fetches
// global (row = l&15, kgroup = l>>4); LDS chunk is thus k-group-major:
// fragment (row, kg) at ushort offset (row>>4)*512 + kg*128 + (row&15)*8.
// Fragment reads become lane-consecutive 16B slots -> conflict-free
// (old [128][32] linear layout had 64B row stride = ~16-way conflict on
// every ds_read_b128). Bit-identical operands, only LDS placement changes.
// C/D layout (m74/m101 verified): col=lane&31, row=(reg&3)+8*(reg>>2)+4*(lane>>5).
// XCD-aware bijective chunked swizzle (m204).

template <bool F16OUT, bool BR>
__global__ __launch_bounds__(256, 4) void gemm_f16_kernel(
    const ushort* __restrict__ A, const ushort* __restrict__ Bw,
    const float* __restrict__ bias,
    float* __restrict__ Cf, ushort* __restrict__ Ch,
    int M, int K, int Nd) {
    __shared__ ushort At[2][128 * 32];
    __shared__ ushort Bt[2][128 * 32];
    int tid = threadIdx.x;

    int nwg = gridDim.x * gridDim.y;
    int id = blockIdx.y * gridDim.x + blockIdx.x;
    int q = nwg >> 3, r8 = nwg & 7;
    int c = id & 7, s = id >> 3;
    int logical = (c < r8) ? c * (q + 1) + s : r8 * (q + 1) + (c - r8) * q + s;
    int bx = logical % gridDim.x, by = logical / gridDim.x;
    int bm = by * 128, bn = bx * 128;

    int lane = tid & 63;
    int wave = tid >> 6;
    int l31 = lane & 31, q2 = lane >> 5;  // 0/1
    int wm = (wave & 1) * 64, wn = (wave >> 1) * 64;

    // staging geometry (transposed map): lane -> (row l&15, kgroup l>>4)
    int rl = lane & 15;
    int kgl = lane >> 4;   // 0..3, each 8 ushorts of the 32-k step

    f32x16 acc[2][2];
#pragma unroll
    for (int i = 0; i < 2; ++i)
#pragma unroll
        for (int j = 0; j < 2; ++j)
#pragma unroll
            for (int r = 0; r < 16; ++r) acc[i][j][r] = 0.0f;

    // per-lane global row indices (clamped; clamped rows produce garbage that is
    // discarded by the epilogue bounds checks)
    int arow0 = bm + wave * 32 + rl;       if (arow0 >= M) arow0 = M - 1;
    int arow1 = bm + wave * 32 + 16 + rl;  if (arow1 >= M) arow1 = M - 1;
    int brow0 = bn + wave * 32 + rl;       if (brow0 >= Nd) brow0 = Nd - 1;
    int brow1 = bn + wave * 32 + 16 + rl;  if (brow1 >= Nd) brow1 = Nd - 1;
    const ushort* Ap0 = A + (size_t)arow0 * K + kgl * 8;
    const ushort* Ap1 = A + (size_t)arow1 * K + kgl * 8;
    const ushort* Bp0 = Bw + (size_t)brow0 * K + kgl * 8;
    const ushort* Bp1 = Bw + (size_t)brow1 * K + kgl * 8;

    // chunk c (16 rows) occupies ushorts [c*512, c*512+512)
    auto stage = [&](int buf, int k0) {
        gload16(Ap0 + k0, &At[buf][(wave * 2) * 512]);
        gload16(Ap1 + k0, &At[buf][(wave * 2 + 1) * 512]);
        gload16(Bp0 + k0, &Bt[buf][(wave * 2) * 512]);
        gload16(Bp1 + k0, &Bt[buf][(wave * 2 + 1) * 512]);
    };

    stage(0, 0);
    int buf = 0;
    for (int k0 = 0; k0 < K; k0 += 32, buf ^= 1) {
        __syncthreads();  // drains vmcnt -> buf ready; all waves done reading buf^1
        if (k0 + 32 < K) stage(buf ^ 1, k0 + 32);

        f16x8 af[2][2];
#pragma unroll
        for (int i = 0; i < 2; ++i) {
            int R = wm + i * 32 + l31;
            const ushort* ar = &At[buf][(R >> 4) * 512 + (R & 15) * 8];
            af[i][0] = *(const f16x8*)(ar + q2 * 128);        // k = q2*8
            af[i][1] = *(const f16x8*)(ar + (2 + q2) * 128);  // k = 16+q2*8
        }
#pragma unroll
        for (int j = 0; j < 2; ++j) {
            int R = wn + j * 32 + l31;
            const ushort* br = &Bt[buf][(R >> 4) * 512 + (R & 15) * 8];
            f16x8 b0 = *(const f16x8*)(br + q2 * 128);
            f16x8 b1 = *(const f16x8*)(br + (2 + q2) * 128);
#pragma unroll
            for (int i = 0; i < 2; ++i) {
                acc[i][j] = __builtin_amdgcn_mfma_f32_32x32x16_f16(af[i][0], b0, acc[i][j], 0, 0, 0);
                acc[i][j] = __builtin_amdgcn_mfma_f32_32x32x16_f16(af[i][1], b1, acc[i][j], 0, 0, 0);
            }
        }
    }

    // epilogue: m = bm+wm+i*32+(r&3)+8*(r>>2)+4*q2, n = bn+wn+j*32+l31
#pragma unroll
    for (int j = 0; j < 2; ++j) {
        int n = bn + wn + j * 32 + l31;
        if (n >= Nd) continue;
        float bv = BR ? bias[n] : 0.0f;
#pragma unroll
        for (int i = 0; i < 2; ++i) {
            int mb = bm + wm + i * 32 + 4 * q2;
#pragma unroll
            for (int r = 0; r < 16; ++r) {
                int m = mb + (r & 3) + 8 * (r >> 2);
                if (m >= M) continue;
                float v = acc[i][j][r];
                if (BR) v = fmaxf(v + bv, 0.0f);
                if (F16OUT) {
                    Ch[(size_t)m * Nd + n] = f2h(v);
                } else {
                    Cf[(size_t)m * Nd + n] = v;
                }
            }
        }
    }
}

// ---------------- fp32 GEMM, 64x64x16 tile, 4x4/thread (small layers) ----------------
// F16IN: A is fp16; F16OUT: write fp16.

template <bool BIASRELU, bool F16IN, bool F16OUT>
__global__ __launch_bounds__(256, 4) void gemm_small_kernel(
    const float* __restrict__ A, const float* __restrict__ W,
    const float* __restrict__ bias, float* __restrict__ C,
    ushort* __restrict__ Ch,
    int M, int K, int Nd) {
    const int BK = 16;
    __shared__ float As[BK][68];
    __shared__ float Ws[BK][68];
    int bm = blockIdx.y * 64;
    int bn = blockIdx.x * 64;
    int tid = threadIdx.x;
    int tx = tid & 15;
    int ty = tid >> 4;

    int ar = tid >> 2;
    int ac = (tid & 3) * 4;
    int wcol = tid & 63;
    int wk0 = (tid >> 6) * 4;

    float acc[4][4];
#pragma unroll
    for (int i = 0; i < 4; ++i)
#pragma unroll
        for (int j = 0; j < 4; ++j) acc[i][j] = 0.0f;

    for (int k0 = 0; k0 < K; k0 += BK) {
        int gm = bm + ar;
        float a0 = 0.f, a1 = 0.f, a2 = 0.f, a3 = 0.f;
        if (gm < M) {
            int gk = k0 + ac;
            if (F16IN) {
                const ushort* ap = (const ushort*)A + (size_t)gm * K;
                a0 = (gk + 0 < K) ? h2f(ap[gk + 0]) : 0.f;
                a1 = (gk + 1 < K) ? h2f(ap[gk + 1]) : 0.f;
                a2 = (gk + 2 < K) ? h2f(ap[gk + 2]) : 0.f;
                a3 = (gk + 3 < K) ? h2f(ap[gk + 3]) : 0.f;
            } else {
                const float* ap = &A[(size_t)gm * K];
                a0 = (gk + 0 < K) ? ap[gk + 0] : 0.f;
                a1 = (gk + 1 < K) ? ap[gk + 1] : 0.f;
                a2 = (gk + 2 < K) ? ap[gk + 2] : 0.f;
                a3 = (gk + 3 < K) ? ap[gk + 3] : 0.f;
            }
        }
        float w0 = 0.f, w1 = 0.f, w2 = 0.f, w3 = 0.f;
        if (bn + wcol < Nd) {
            int gk = k0 + wk0;
            w0 = (gk + 0 < K) ? W[(size_t)(gk + 0) * Nd + bn + wcol] : 0.f;
            w1 = (gk + 1 < K) ? W[(size_t)(gk + 1) * Nd + bn + wcol] : 0.f;
            w2 = (gk + 2 < K) ? W[(size_t)(gk + 2) * Nd + bn + wcol] : 0.f;
            w3 = (gk + 3 < K) ? W[(size_t)(gk + 3) * Nd + bn + wcol] : 0.f;
        }
        __syncthreads();
        As[ac + 0][ar] = a0;
        As[ac + 1][ar] = a1;
        As[ac + 2][ar] = a2;
        As[ac + 3][ar] = a3;
        Ws[wk0 + 0][wcol] = w0;
        Ws[wk0 + 1][wcol] = w1;
        Ws[wk0 + 2][wcol] = w2;
        Ws[wk0 + 3][wcol] = w3;
        __syncthreads();
#pragma unroll
        for (int kk = 0; kk < BK; ++kk) {
            float4 a = *(const float4*)&As[kk][ty * 4];
            float4 b = *(const float4*)&Ws[kk][tx * 4];
            float af[4] = {a.x, a.y, a.z, a.w};
            float bf[4] = {b.x, b.y, b.z, b.w};
#pragma unroll
            for (int i = 0; i < 4; ++i)
#pragma unroll
                for (int j = 0; j < 4; ++j) acc[i][j] = fmaf(af[i], bf[j], acc[i][j]);
        }
    }

    int col = bn + tx * 4;
    if (col >= Nd) return;
    float4 bi = make_float4(0.f, 0.f, 0.f, 0.f);
    if (BIASRELU) bi = *(const float4*)&bias[col];
#pragma unroll
    for (int i = 0; i < 4; ++i) {
        int m = bm + ty * 4 + i;
        if (m >= M) continue;
        float4 r = make_float4(acc[i][0], acc[i][1], acc[i][2], acc[i][3]);
        if (BIASRELU) {
            r.x = fmaxf(r.x + bi.x, 0.f); r.y = fmaxf(r.y + bi.y, 0.f);
            r.z = fmaxf(r.z + bi.z, 0.f); r.w = fmaxf(r.w + bi.w, 0.f);
        }
        if (F16OUT) {
            ushort4 hv;
            hv.x = f2h(r.x); hv.y = f2h(r.y); hv.z = f2h(r.z); hv.w = f2h(r.w);
            *(ushort4*)&Ch[(size_t)m * Nd + col] = hv;
        } else {
            *(float4*)&C[(size_t)m * Nd + col] = r;
        }
    }
}

// ---------------- launch ----------------

extern "C" void kernel_launch(void* const* d_in, const int* in_sizes, int n_in,
                              void* d_out, int out_size, void* d_ws, size_t ws_size,
                              hipStream_t stream) {
    const float* x = (const float*)d_in[0];
    const int* ei = (const int*)d_in[1];
    const int* e_src = ei;
    const int* e_dst = ei + NE;
    const float* W1 = (const float*)d_in[2];
    const float* b1 = (const float*)d_in[3];
    const float* W2 = (const float*)d_in[4];
    const float* b2 = (const float*)d_in[5];
    const float* W3 = (const float*)d_in[6];
    const float* b3 = (const float*)d_in[7];
    const float* W4 = (const float*)d_in[8];
    const float* b4 = (const float*)d_in[9];
    const float* W5 = (const float*)d_in[10];
    const float* b5 = (const float*)d_in[11];
    const float* W6 = (const float*)d_in[12];
    const float* b6 = (const float*)d_in[13];
    float* out = (float*)d_out;

    // ---- workspace layout: 256B-aligned regions, liveness-checked ping-pong ----
    char* p = (char*)d_ws;
    auto take = [&p](size_t nbytes) {
        char* q = p;
        p += (nbytes + 255) & ~(size_t)255;
        return q;
    };
    char* RA = take((size_t)NN * 1024);   // 1 KB/node
    char* RB = take((size_t)NN * 1024);   // 1 KB/node
    char* RC = take((size_t)NN * 2048);   // 2 KB/node
    float* dinv = (float*)take((size_t)NN * 4);
    int* row_ptr = (int*)take((size_t)(NN + 1) * 4);
    int* col_src = (int*)take((size_t)NE * 4);
    unsigned* ebuf = (unsigned*)take((size_t)NE * 4);
    int* gcnt = (int*)take(256 * 4);
    int* bbase = (int*)take(256 * 4);
    int* bcur = (int*)take(256 * 4);
    ushort* W2th = (ushort*)take((size_t)64 * 256 * 2);
    ushort* W3th = (ushort*)take((size_t)256 * 512 * 2);
    ushort* W4th = (ushort*)take((size_t)512 * 256 * 2);
    ushort* W5th = (ushort*)take((size_t)256 * 64 * 2);

    // Buffer timeline (reads left, writes right; no overlap within a dispatch):
    //   L1g:  x        -> H1h (RA)       [fp16 out]
    //   agg1: H1h (RA) -> X1h (RB)       [fp16 in/out, bias+relu]
    //   agg2: X1h (RB) -> A2h (RC)       [fp16 in/out]
    //   L2 :  A2h (RC) -> X2h (RA)       [fp16 out, bias+relu]
    //   agg3: X2h (RA) -> A3h (RB)       [fp16 in/out]
    //   L3 :  A3h (RB) -> X3h (RC)       [fp16 out, bias+relu]
    //   L4 :  X3h (RC) -> H4h (RA)       [fp16 out]
    //   agg4: H4h (RA) -> X4h (RB)       [fp16 in/out, bias+relu]
    //   L5 :  X4h (RB) -> H5h (RA)       [fp16 out]
    //   agg5: H5h (RA) -> X5h (RB)       [fp16 in/out, bias+relu]
    //   L6 :  X5h (RB) -> H6f (RA)       [fp16 in, f32 out]
    //   agg6: H6f (RA) -> out            [f32]
    ushort* H1h = (ushort*)RA;                     // NN x 64 fp16
    ushort* X1h = (ushort*)RB;                     // NN x 64 fp16
    ushort* A2h = (ushort*)RC;                     // NN x 64 fp16
    ushort* X2h = (ushort*)RA;                     // NN x 256 fp16
    ushort* A3h = (ushort*)RB;                     // NN x 256 fp16
    ushort* X3h = (ushort*)RC;                     // NN x 512 fp16
    ushort* H4h = (ushort*)RA;                     // NN x 256 fp16
    ushort* X4h = (ushort*)RB;                     // NN x 256 fp16
    ushort* H5h = (ushort*)RA;                     // NN x 64 fp16
    ushort* X5h = (ushort*)RB;                     // NN x 64 fp16
    float* H6f = (float*)RA;                       // NN x 16 f32

    // CSR build (bucket sort; also produces row_ptr + dinv)
    zero_int_kernel<<<1, 256, 0, stream>>>(gcnt, 256);
    bucket_hist_kernel<<<EB_BLOCKS, 256, 0, stream>>>(e_dst, gcnt);
    bucket_scan_kernel<<<1, 256, 0, stream>>>(gcnt, bbase, bcur, row_ptr);
    edge_bin_kernel<<<EB_BLOCKS, 256, 0, stream>>>(e_src, e_dst, bcur, ebuf);
    bucket_sort_kernel<<<NBUK, 256, 0, stream>>>(bbase, ebuf, col_src, row_ptr, dinv);

    // fused weight splits (W2,W3,W4,W5) -> fp16 single plane
    split_all_kernel<<<(294912 + 255) / 256, 256, 0, stream>>>(
        W2, W3, W4, W5, W2th, W3th, W4th, W5th);

    const int aggGrid256 = (NN + 3) / 4;    // WD=256: 4 nodes/block
    const int aggGrid64v = (NN + 15) / 16;  // WD=64: 16 nodes/block
    const int aggGrid16v = (NN + 63) / 64;  // WD=16: 64 nodes/block
    const int mrows = (NN + 127) / 128;     // 391

    // L1 (GEMM-first): H1 = x@W1 (fp16 out) ; X1 = relu(S*H1+b1) (fp16)
    {
        dim3 g(1, (NN + 63) / 64);
        gemm_small_kernel<false, false, true><<<g, 256, 0, stream>>>(
            x, W1, nullptr, nullptr, H1h, NN, 35, 64);
    }
    aggregate_vec_kernel<64, true, true, true, true><<<aggGrid64v, 256, 0, stream>>>(
        (const float*)H1h, dinv, row_ptr, col_src, b1, nullptr, X1h);
    // L2: agg(X1,64) -> A2h fp16 ; X2 = relu(A2@W2+b2) -> X2h (256 fp16)
    aggregate_vec_kernel<64, false, false, true, true><<<aggGrid64v, 256, 0, stream>>>(
        (const float*)X1h, dinv, row_ptr, col_src, nullptr, nullptr, A2h);
    {
        dim3 g(2, mrows);
        gemm_f16_kernel<true, true><<<g, 256, 0, stream>>>(A2h, W2th, b2,
                                                           nullptr, X2h, NN, 64, 256);
    }
    // L3: agg(X2 fp16,256) -> A3h fp16 ; X3 = relu(A3@W3+b3) -> X3h (512 fp16)
    aggregate_vec_kernel<256, false, false, true, true><<<aggGrid256, 256, 0, stream>>>(
        (const float*)X2h, dinv, row_ptr, col_src, nullptr, nullptr, A3h);
    {
        dim3 g(4, mrows);
        gemm_f16_kernel<true, true><<<g, 256, 0, stream>>>(A3h, W3th, b3,
                                                           nullptr, X3h, NN, 256, 512);
    }
    // L4: H4 = X3@W4 -> H4h (256 fp16) ; X4 = relu(S*H4+b4) -> X4h (256 fp16)
    {
        dim3 g(2, mrows);
        gemm_f16_kernel<true, false><<<g, 256, 0, stream>>>(X3h, W4th, nullptr,
                                                            nullptr, H4h, NN, 512, 256);
    }
    aggregate_vec_kernel<256, true, true, true, true><<<aggGrid256, 256, 0, stream>>>(
        (const float*)H4h, dinv, row_ptr, col_src, b4, nullptr, X4h);
    // L5: H5 = X4@W5 -> H5h (64 fp16) ; X5 = relu(S*H5+b5) -> X5h (64 fp16)
    {
        dim3 g(1, mrows);
        gemm_f16_kernel<true, false><<<g, 256, 0, stream>>>(X4h, W5th, nullptr,
                                                            nullptr, H5h, NN, 256, 64);
    }
    aggregate_vec_kernel<64, true, true, true, true><<<aggGrid64v, 256, 0, stream>>>(
        (const float*)H5h, dinv, row_ptr, col_src, b5, nullptr, X5h);
    // L6: H6 = X5@W6 -> H6f (16 f32) ; out = S*H6 + b6
    {
        dim3 g(1, (NN + 63) / 64);
        gemm_small_kernel<false, true, false><<<g, 256, 0, stream>>>(
            (const float*)X5h, W6, nullptr, H6f, nullptr, NN, 64, 16);
    }
    aggregate_vec_kernel<16, true, false, false, false><<<aggGrid16v, 256, 0, stream>>>(
        H6f, dinv, row_ptr, col_src, b6, out, nullptr);
}

// Round 8
// 425.313 us; speedup vs baseline: 1.0623x; 1.0623x over previous
//
#include <hip/hip_runtime.h>

#define NN 50000
#define NE 800000
#define NBUK 196          // ceil(NN/256)
#define EB_BLOCKS 196     // ceil(NE/4096)
#define BCAP 5120         // per-bucket LDS cap; mean 4081, sigma 64 -> +16 sigma

typedef __attribute__((ext_vector_type(8))) _Float16 f16x8;
typedef __attribute__((ext_vector_type(16))) float f32x16;
typedef __attribute__((ext_vector_type(4))) _Float16 half4v;

__device__ inline ushort f2h(float f) {
    _Float16 h = (_Float16)f;  // RNE
    union { _Float16 h; ushort u; } v; v.h = h;
    return v.u;
}
__device__ inline float h2f(ushort u) {
    union { _Float16 h; ushort u; } v; v.u = u;
    return (float)v.h;
}

// async global->LDS, 16B per lane; LDS dest is wave-uniform base + lane*16 (m104)
typedef unsigned int u32_g __attribute__((address_space(1)));
typedef unsigned int u32_l __attribute__((address_space(3)));
__device__ inline void gload16(const ushort* g, ushort* l) {
    __builtin_amdgcn_global_load_lds((const u32_g*)g, (u32_l*)l, 16, 0, 0);
}

// row-group load: 4 contiguous elems at group index idx (fp32: 16B, fp16: 8B)
template <bool F16>
__device__ inline float4 ldrow(const float* __restrict__ H, size_t idx) {
    if (F16) {
        half4v h = ((const half4v*)H)[idx];
        return make_float4((float)h.x, (float)h.y, (float)h.z, (float)h.w);
    } else {
        return ((const float4*)H)[idx];
    }
}

// ---------------- CSR build: write-coalesced 2-level bucket sort ----------------

__global__ __launch_bounds__(256) void zero_int_kernel(int* __restrict__ p, int n) {
    int i = blockIdx.x * 256 + threadIdx.x;
    if (i < n) p[i] = 0;
}

// per-block LDS histogram of dst>>8 -> 196 global atomics per block
__global__ __launch_bounds__(256) void bucket_hist_kernel(const int* __restrict__ dst,
                                                          int* __restrict__ gcnt) {
    __shared__ int cnt[256];
    int tid = threadIdx.x;
    cnt[tid] = 0;
    __syncthreads();
    int e0 = blockIdx.x * 4096;
#pragma unroll
    for (int i = 0; i < 16; ++i) {
        int e = e0 + i * 256 + tid;
        if (e < NE) atomicAdd(&cnt[dst[e] >> 8], 1);
    }
    __syncthreads();
    if (tid < NBUK && cnt[tid] > 0) atomicAdd(&gcnt[tid], cnt[tid]);
}

// 1-block exclusive scan of bucket counts -> bucket bases (+ phase-A cursors)
__global__ __launch_bounds__(256) void bucket_scan_kernel(const int* __restrict__ gcnt,
                                                          int* __restrict__ bbase,
                                                          int* __restrict__ bcur,
                                                          int* __restrict__ row_ptr) {
    __shared__ int s[256];
    int tid = threadIdx.x;
    int v = (tid < NBUK) ? gcnt[tid] : 0;
    s[tid] = v;
    __syncthreads();
    for (int o = 1; o < 256; o <<= 1) {
        int t = (tid >= o) ? s[tid - o] : 0;
        __syncthreads();
        s[tid] += t;
        __syncthreads();
    }
    int excl = s[tid] - v;
    if (tid < NBUK) { bbase[tid] = excl; bcur[tid] = excl; }
    if (tid == 0) row_ptr[NN] = NE;
}

// Phase A: partition 4096 edges/block into bucket-major intermediate buffer.
// Pack = (src<<8) | (dst&255): src<50000<2^16, so 24 bits fit one u32.
__global__ __launch_bounds__(256) void edge_bin_kernel(const int* __restrict__ src,
                                                       const int* __restrict__ dst,
                                                       int* __restrict__ bcur,
                                                       unsigned* __restrict__ ebuf) {
    __shared__ int cnt[256];
    __shared__ int off[256];
    __shared__ int cur[256];
    __shared__ int gbase[256];
    __shared__ unsigned stage[4096];
    __shared__ unsigned char bmap[4096];
    int tid = threadIdx.x;
    int e0 = blockIdx.x * 4096;
    int filled = min(4096, NE - e0);
    cnt[tid] = 0;
    __syncthreads();
#pragma unroll
    for (int i = 0; i < 16; ++i) {
        int e = e0 + i * 256 + tid;
        if (e < NE) atomicAdd(&cnt[dst[e] >> 8], 1);
    }
    __syncthreads();
    int v = cnt[tid];
    off[tid] = v;
    __syncthreads();
    for (int o = 1; o < 256; o <<= 1) {
        int t = (tid >= o) ? off[tid - o] : 0;
        __syncthreads();
        off[tid] += t;
        __syncthreads();
    }
    int excl = off[tid] - v;
    __syncthreads();
    off[tid] = excl;     // now exclusive
    cur[tid] = excl;
    if (tid < NBUK && v > 0) gbase[tid] = atomicAdd(&bcur[tid], v);
    __syncthreads();
#pragma unroll
    for (int i = 0; i < 16; ++i) {
        int e = e0 + i * 256 + tid;
        if (e < NE) {
            int d = dst[e];
            int b = d >> 8;
            int p = atomicAdd(&cur[b], 1);
            stage[p] = ((unsigned)src[e] << 8) | (unsigned)(d & 255);
            bmap[p] = (unsigned char)b;
        }
    }
    __syncthreads();
    for (int s2 = tid; s2 < filled; s2 += 256) {
        int b = bmap[s2];
        ebuf[gbase[b] + (s2 - off[b])] = stage[s2];
    }
}

// Phase B: one block per bucket (256 nodes). Exact per-node counts -> row_ptr
// segment + dinv; LDS counting-sort; coalesced flush.
__global__ __launch_bounds__(256) void bucket_sort_kernel(const int* __restrict__ bbase,
                                                          const unsigned* __restrict__ ebuf,
                                                          int* __restrict__ col_src,
                                                          int* __restrict__ row_ptr,
                                                          float* __restrict__ dinv) {
    __shared__ int cnt[256];
    __shared__ int off[256];
    __shared__ int cur[256];
    __shared__ unsigned pk[BCAP];
    __shared__ int outv[BCAP];
    int tid = threadIdx.x;
    int nb = blockIdx.x;
    int n0 = nb << 8;
    int base = bbase[nb];
    int cntE = ((nb + 1 < NBUK) ? bbase[nb + 1] : NE) - base;
    cnt[tid] = 0;
    __syncthreads();
    for (int e = tid; e < cntE; e += 256) {
        unsigned p = ebuf[base + e];
        pk[e] = p;
        atomicAdd(&cnt[(int)(p & 255u)], 1);
    }
    __syncthreads();
    int v = cnt[tid];
    off[tid] = v;
    __syncthreads();
    for (int o = 1; o < 256; o <<= 1) {
        int t = (tid >= o) ? off[tid - o] : 0;
        __syncthreads();
        off[tid] += t;
        __syncthreads();
    }
    int excl = off[tid] - v;
    cur[tid] = excl;
    int n = n0 + tid;
    if (n < NN) {
        row_ptr[n] = base + excl;
        dinv[n] = rsqrtf((float)(v + 1));  // +1 self loop
    }
    __syncthreads();
    for (int e = tid; e < cntE; e += 256) {
        unsigned p = pk[e];
        int pos = atomicAdd(&cur[(int)(p & 255u)], 1);
        outv[pos] = (int)(p >> 8);
    }
    __syncthreads();
    for (int e = tid; e < cntE; e += 256) col_src[base + e] = outv[e];
}

// ---- fused weight split+transpose W2..W5: W[K][Nd] fp32 -> [Nd][K] fp16 (single plane) ----

__global__ __launch_bounds__(256) void split_all_kernel(
    const float* __restrict__ W2, const float* __restrict__ W3,
    const float* __restrict__ W4, const float* __restrict__ W5,
    ushort* __restrict__ W2th, ushort* __restrict__ W3th,
    ushort* __restrict__ W4th, ushort* __restrict__ W5th) {
    int i = blockIdx.x * 256 + threadIdx.x;
    const float* W; ushort* Wth; int K, Nd, idx;
    if (i < 16384) {                     // W2: 64x256
        W = W2; Wth = W2th; K = 64; Nd = 256; idx = i;
    } else if (i < 147456) {             // W3: 256x512
        W = W3; Wth = W3th; K = 256; Nd = 512; idx = i - 16384;
    } else if (i < 278528) {             // W4: 512x256
        W = W4; Wth = W4th; K = 512; Nd = 256; idx = i - 147456;
    } else if (i < 294912) {             // W5: 256x64
        W = W5; Wth = W5th; K = 256; Nd = 64; idx = i - 278528;
    } else {
        return;
    }
    int k = idx / Nd, n = idx - k * Nd;
    Wth[(size_t)n * K + k] = f2h(W[idx]);
}

// ------- aggregation: out[v] = dv*sum du*H[u] + dv^2*H[v] (+bias,relu | fp16 out) ----
// vectorized: GS = WD/4 lanes/node, one 4-elem group per lane, 8-deep gather prefetch.
// BW-bound at ~3.7 TB/s on the random-gather fetch path (r0-r4: time scales with
// fetch bytes; r5: column-splitting null-to-negative -> at structural floor).

template <int WD, bool BIAS, bool RELU, bool F16O, bool F16IN>
__global__ __launch_bounds__(256) void aggregate_vec_kernel(
    const float* __restrict__ H, const float* __restrict__ dinv,
    const int* __restrict__ row_ptr, const int* __restrict__ col_src,
    const float* __restrict__ bias, float* __restrict__ out,
    ushort* __restrict__ oh) {
    const int GS = WD / 4;
    const int NPB = 256 / GS;
    int v = blockIdx.x * NPB + (threadIdx.x / GS);
    int lg = threadIdx.x & (GS - 1);
    if (v >= NN) return;
    float dv = dinv[v];
    int beg = row_ptr[v], end = row_ptr[v + 1];
    float4 self = ldrow<F16IN>(H, (size_t)v * GS + lg);
    float4 acc = make_float4(0.f, 0.f, 0.f, 0.f);
    for (int cbeg = beg; cbeg < end; cbeg += GS) {
        int cnt = min(GS, end - cbeg);
        int u_l = (lg < cnt) ? col_src[cbeg + lg] : 0;
        float w_l = (lg < cnt) ? dinv[u_l] : 0.0f;
        int e = 0;
        for (; e + 8 <= cnt; e += 8) {
            int u[8]; float w[8]; float4 h[8];
#pragma unroll
            for (int t = 0; t < 8; ++t) {
                u[t] = __shfl(u_l, e + t, GS);
                w[t] = __shfl(w_l, e + t, GS);
            }
#pragma unroll
            for (int t = 0; t < 8; ++t) h[t] = ldrow<F16IN>(H, (size_t)u[t] * GS + lg);
#pragma unroll
            for (int t = 0; t < 8; ++t) {
                acc.x = fmaf(w[t], h[t].x, acc.x); acc.y = fmaf(w[t], h[t].y, acc.y);
                acc.z = fmaf(w[t], h[t].z, acc.z); acc.w = fmaf(w[t], h[t].w, acc.w);
            }
        }
        for (; e + 4 <= cnt; e += 4) {
            int u[4]; float w[4]; float4 h[4];
#pragma unroll
            for (int t = 0; t < 4; ++t) {
                u[t] = __shfl(u_l, e + t, GS);
                w[t] = __shfl(w_l, e + t, GS);
            }
#pragma unroll
            for (int t = 0; t < 4; ++t) h[t] = ldrow<F16IN>(H, (size_t)u[t] * GS + lg);
#pragma unroll
            for (int t = 0; t < 4; ++t) {
                acc.x = fmaf(w[t], h[t].x, acc.x); acc.y = fmaf(w[t], h[t].y, acc.y);
                acc.z = fmaf(w[t], h[t].z, acc.z); acc.w = fmaf(w[t], h[t].w, acc.w);
            }
        }
        for (; e < cnt; ++e) {
            int u = __shfl(u_l, e, GS);
            float w = __shfl(w_l, e, GS);
            float4 h = ldrow<F16IN>(H, (size_t)u * GS + lg);
            acc.x = fmaf(w, h.x, acc.x); acc.y = fmaf(w, h.y, acc.y);
            acc.z = fmaf(w, h.z, acc.z); acc.w = fmaf(w, h.w, acc.w);
        }
    }
    float dv2 = dv * dv;
    float4 r;
    r.x = fmaf(dv, acc.x, dv2 * self.x);
    r.y = fmaf(dv, acc.y, dv2 * self.y);
    r.z = fmaf(dv, acc.z, dv2 * self.z);
    r.w = fmaf(dv, acc.w, dv2 * self.w);
    if (BIAS) {
        float4 b = ((const float4*)bias)[lg];
        r.x += b.x; r.y += b.y; r.z += b.z; r.w += b.w;
    }
    if (RELU) {
        r.x = fmaxf(r.x, 0.f); r.y = fmaxf(r.y, 0.f);
        r.z = fmaxf(r.z, 0.f); r.w = fmaxf(r.w, 0.f);
    }
    if (F16O) {
        ushort4 hv;
        hv.x = f2h(r.x); hv.y = f2h(r.y); hv.z = f2h(r.z); hv.w = f2h(r.w);
        *(ushort4*)&oh[(size_t)v * WD + lg * 4] = hv;
    } else {
        ((float4*)out)[(size_t)v * GS + lg] = r;
    }
}

// ---------------- f16 MFMA GEMM (32x32x16): C = A @ Wt^T ----------------
// A fp16 exact, W single fp16 plane -> 1 MFMA per fragment pair.
// 128x128 tile, 4 waves 2x2; global_load_lds staging, double-buffered,
// single __syncthreads per K-step.
// STAGING (r8, both-sides XOR swizzle, guide rule #21): staging map is r6's
// coalesced one (lane -> row lane>>2, 4 lanes per 64B row segment), with the
// kgroup XOR-swizzled per lane: kg = (lane&3) ^ ((lane>>4)&3). Global lines
// unchanged (permutation within each 64B segment); LDS dest stays linear.
// Fragment (row R, kg) then lives at ushort offset
//   (R>>4)*512 + (R&15)*32 + ((kg ^ ((R>>2)&3)))*8
// -> every ds_read_b128 spreads uniformly over all 8 bank quads (conflict-free;
// the r6 linear layout was ~8-way conflicted, r7's transposed map broke global
// coalescing instead). Bit-identical operands.
// C/D layout (m74/m101 verified): col=lane&31, row=(reg&3)+8*(reg>>2)+4*(lane>>5).
// XCD-aware bijective chunked swizzle (m204).

template <bool F16OUT, bool BR>
__global__ __launch_bounds__(256, 4) void gemm_f16_kernel(
    const ushort* __restrict__ A, const ushort* __restrict__ Bw,
    const float* __restrict__ bias,
    float* __restrict__ Cf, ushort* __restrict__ Ch,
    int M, int K, int Nd) {
    __shared__ ushort At[2][128 * 32];
    __shared__ ushort Bt[2][128 * 32];
    int tid = threadIdx.x;

    int nwg = gridDim.x * gridDim.y;
    int id = blockIdx.y * gridDim.x + blockIdx.x;
    int q = nwg >> 3, r8 = nwg & 7;
    int c = id & 7, s = id >> 3;
    int logical = (c < r8) ? c * (q + 1) + s : r8 * (q + 1) + (c - r8) * q + s;
    int bx = logical % gridDim.x, by = logical / gridDim.x;
    int bm = by * 128, bn = bx * 128;

    int lane = tid & 63;
    int wave = tid >> 6;
    int l31 = lane & 31, q2 = lane >> 5;  // 0/1
    int wm = (wave & 1) * 64, wn = (wave >> 1) * 64;

    // staging geometry: lane -> (row lane>>2, kgroup (lane&3)^((lane>>4)&3))
    int rstg = lane >> 2;                              // 0..15 row within chunk
    int kswz = ((lane & 3) ^ ((lane >> 4) & 3)) * 8;   // swizzled kgroup (ushorts)

    f32x16 acc[2][2];
#pragma unroll
    for (int i = 0; i < 2; ++i)
#pragma unroll
        for (int j = 0; j < 2; ++j)
#pragma unroll
            for (int r = 0; r < 16; ++r) acc[i][j][r] = 0.0f;

    // per-lane global row indices (clamped; clamped rows produce garbage that is
    // discarded by the epilogue bounds checks)
    int arow0 = bm + wave * 32 + rstg;       if (arow0 >= M) arow0 = M - 1;
    int arow1 = bm + wave * 32 + 16 + rstg;  if (arow1 >= M) arow1 = M - 1;
    int brow0 = bn + wave * 32 + rstg;       if (brow0 >= Nd) brow0 = Nd - 1;
    int brow1 = bn + wave * 32 + 16 + rstg;  if (brow1 >= Nd) brow1 = Nd - 1;
    const ushort* Ap0 = A + (size_t)arow0 * K + kswz;
    const ushort* Ap1 = A + (size_t)arow1 * K + kswz;
    const ushort* Bp0 = Bw + (size_t)brow0 * K + kswz;
    const ushort* Bp1 = Bw + (size_t)brow1 * K + kswz;

    // chunk c (16 rows) occupies ushorts [c*512, c*512+512)
    auto stage = [&](int buf, int k0) {
        gload16(Ap0 + k0, &At[buf][(wave * 2) * 512]);
        gload16(Ap1 + k0, &At[buf][(wave * 2 + 1) * 512]);
        gload16(Bp0 + k0, &Bt[buf][(wave * 2) * 512]);
        gload16(Bp1 + k0, &Bt[buf][(wave * 2 + 1) * 512]);
    };

    stage(0, 0);
    int buf = 0;
    for (int k0 = 0; k0 < K; k0 += 32, buf ^= 1) {
        __syncthreads();  // drains vmcnt -> buf ready; all waves done reading buf^1
        if (k0 + 32 < K) stage(buf ^ 1, k0 + 32);

        f16x8 af[2][2];
#pragma unroll
        for (int i = 0; i < 2; ++i) {
            int R = wm + i * 32 + l31;
            int aa = (R >> 2) & 3;
            const ushort* ar = &At[buf][(R >> 4) * 512 + (R & 15) * 32];
            af[i][0] = *(const f16x8*)(ar + (q2 ^ aa) * 8);
            af[i][1] = *(const f16x8*)(ar + ((2 + q2) ^ aa) * 8);
        }
#pragma unroll
        for (int j = 0; j < 2; ++j) {
            int R = wn + j * 32 + l31;
            int aa = (R >> 2) & 3;
            const ushort* br = &Bt[buf][(R >> 4) * 512 + (R & 15) * 32];
            f16x8 b0 = *(const f16x8*)(br + (q2 ^ aa) * 8);
            f16x8 b1 = *(const f16x8*)(br + ((2 + q2) ^ aa) * 8);
#pragma unroll
            for (int i = 0; i < 2; ++i) {
                acc[i][j] = __builtin_amdgcn_mfma_f32_32x32x16_f16(af[i][0], b0, acc[i][j], 0, 0, 0);
                acc[i][j] = __builtin_amdgcn_mfma_f32_32x32x16_f16(af[i][1], b1, acc[i][j], 0, 0, 0);
            }
        }
    }

    // epilogue: m = bm+wm+i*32+(r&3)+8*(r>>2)+4*q2, n = bn+wn+j*32+l31
#pragma unroll
    for (int j = 0; j < 2; ++j) {
        int n = bn + wn + j * 32 + l31;
        if (n >= Nd) continue;
        float bv = BR ? bias[n] : 0.0f;
#pragma unroll
        for (int i = 0; i < 2; ++i) {
            int mb = bm + wm + i * 32 + 4 * q2;
#pragma unroll
            for (int r = 0; r < 16; ++r) {
                int m = mb + (r & 3) + 8 * (r >> 2);
                if (m >= M) continue;
                float v = acc[i][j][r];
                if (BR) v = fmaxf(v + bv, 0.0f);
                if (F16OUT) {
                    Ch[(size_t)m * Nd + n] = f2h(v);
                } else {
                    Cf[(size_t)m * Nd + n] = v;
                }
            }
        }
    }
}

// ---------------- fp32 GEMM, 64x64x16 tile, 4x4/thread (small layers) ----------------
// F16IN: A is fp16; F16OUT: write fp16.

template <bool BIASRELU, bool F16IN, bool F16OUT>
__global__ __launch_bounds__(256, 4) void gemm_small_kernel(
    const float* __restrict__ A, const float* __restrict__ W,
    const float* __restrict__ bias, float* __restrict__ C,
    ushort* __restrict__ Ch,
    int M, int K, int Nd) {
    const int BK = 16;
    __shared__ float As[BK][68];
    __shared__ float Ws[BK][68];
    int bm = blockIdx.y * 64;
    int bn = blockIdx.x * 64;
    int tid = threadIdx.x;
    int tx = tid & 15;
    int ty = tid >> 4;

    int ar = tid >> 2;
    int ac = (tid & 3) * 4;
    int wcol = tid & 63;
    int wk0 = (tid >> 6) * 4;

    float acc[4][4];
#pragma unroll
    for (int i = 0; i < 4; ++i)
#pragma unroll
        for (int j = 0; j < 4; ++j) acc[i][j] = 0.0f;

    for (int k0 = 0; k0 < K; k0 += BK) {
        int gm = bm + ar;
        float a0 = 0.f, a1 = 0.f, a2 = 0.f, a3 = 0.f;
        if (gm < M) {
            int gk = k0 + ac;
            if (F16IN) {
                const ushort* ap = (const ushort*)A + (size_t)gm * K;
                a0 = (gk + 0 < K) ? h2f(ap[gk + 0]) : 0.f;
                a1 = (gk + 1 < K) ? h2f(ap[gk + 1]) : 0.f;
                a2 = (gk + 2 < K) ? h2f(ap[gk + 2]) : 0.f;
                a3 = (gk + 3 < K) ? h2f(ap[gk + 3]) : 0.f;
            } else {
                const float* ap = &A[(size_t)gm * K];
                a0 = (gk + 0 < K) ? ap[gk + 0] : 0.f;
                a1 = (gk + 1 < K) ? ap[gk + 1] : 0.f;
                a2 = (gk + 2 < K) ? ap[gk + 2] : 0.f;
                a3 = (gk + 3 < K) ? ap[gk + 3] : 0.f;
            }
        }
        float w0 = 0.f, w1 = 0.f, w2 = 0.f, w3 = 0.f;
        if (bn + wcol < Nd) {
            int gk = k0 + wk0;
            w0 = (gk + 0 < K) ? W[(size_t)(gk + 0) * Nd + bn + wcol] : 0.f;
            w1 = (gk + 1 < K) ? W[(size_t)(gk + 1) * Nd + bn + wcol] : 0.f;
            w2 = (gk + 2 < K) ? W[(size_t)(gk + 2) * Nd + bn + wcol] : 0.f;
            w3 = (gk + 3 < K) ? W[(size_t)(gk + 3) * Nd + bn + wcol] : 0.f;
        }
        __syncthreads();
        As[ac + 0][ar] = a0;
        As[ac + 1][ar] = a1;
        As[ac + 2][ar] = a2;
        As[ac + 3][ar] = a3;
        Ws[wk0 + 0][wcol] = w0;
        Ws[wk0 + 1][wcol] = w1;
        Ws[wk0 + 2][wcol] = w2;
        Ws[wk0 + 3][wcol] = w3;
        __syncthreads();
#pragma unroll
        for (int kk = 0; kk < BK; ++kk) {
            float4 a = *(const float4*)&As[kk][ty * 4];
            float4 b = *(const float4*)&Ws[kk][tx * 4];
            float af[4] = {a.x, a.y, a.z, a.w};
            float bf[4] = {b.x, b.y, b.z, b.w};
#pragma unroll
            for (int i = 0; i < 4; ++i)
#pragma unroll
                for (int j = 0; j < 4; ++j) acc[i][j] = fmaf(af[i], bf[j], acc[i][j]);
        }
    }

    int col = bn + tx * 4;
    if (col >= Nd) return;
    float4 bi = make_float4(0.f, 0.f, 0.f, 0.f);
    if (BIASRELU) bi = *(const float4*)&bias[col];
#pragma unroll
    for (int i = 0; i < 4; ++i) {
        int m = bm + ty * 4 + i;
        if (m >= M) continue;
        float4 r = make_float4(acc[i][0], acc[i][1], acc[i][2], acc[i][3]);
        if (BIASRELU) {
            r.x = fmaxf(r.x + bi.x, 0.f); r.y = fmaxf(r.y + bi.y, 0.f);
            r.z = fmaxf(r.z + bi.z, 0.f); r.w = fmaxf(r.w + bi.w, 0.f);
        }
        if (F16OUT) {
            ushort4 hv;
            hv.x = f2h(r.x); hv.y = f2h(r.y); hv.z = f2h(r.z); hv.w = f2h(r.w);
            *(ushort4*)&Ch[(size_t)m * Nd + col] = hv;
        } else {
            *(float4*)&C[(size_t)m * Nd + col] = r;
        }
    }
}

// ---------------- launch ----------------

extern "C" void kernel_launch(void* const* d_in, const int* in_sizes, int n_in,
                              void* d_out, int out_size, void* d_ws, size_t ws_size,
                              hipStream_t stream) {
    const float* x = (const float*)d_in[0];
    const int* ei = (const int*)d_in[1];
    const int* e_src = ei;
    const int* e_dst = ei + NE;
    const float* W1 = (const float*)d_in[2];
    const float* b1 = (const float*)d_in[3];
    const float* W2 = (const float*)d_in[4];
    const float* b2 = (const float*)d_in[5];
    const float* W3 = (const float*)d_in[6];
    const float* b3 = (const float*)d_in[7];
    const float* W4 = (const float*)d_in[8];
    const float* b4 = (const float*)d_in[9];
    const float* W5 = (const float*)d_in[10];
    const float* b5 = (const float*)d_in[11];
    const float* W6 = (const float*)d_in[12];
    const float* b6 = (const float*)d_in[13];
    float* out = (float*)d_out;

    // ---- workspace layout: 256B-aligned regions, liveness-checked ping-pong ----
    char* p = (char*)d_ws;
    auto take = [&p](size_t nbytes) {
        char* q = p;
        p += (nbytes + 255) & ~(size_t)255;
        return q;
    };
    char* RA = take((size_t)NN * 1024);   // 1 KB/node
    char* RB = take((size_t)NN * 1024);   // 1 KB/node
    char* RC = take((size_t)NN * 2048);   // 2 KB/node
    float* dinv = (float*)take((size_t)NN * 4);
    int* row_ptr = (int*)take((size_t)(NN + 1) * 4);
    int* col_src = (int*)take((size_t)NE * 4);
    unsigned* ebuf = (unsigned*)take((size_t)NE * 4);
    int* gcnt = (int*)take(256 * 4);
    int* bbase = (int*)take(256 * 4);
    int* bcur = (int*)take(256 * 4);
    ushort* W2th = (ushort*)take((size_t)64 * 256 * 2);
    ushort* W3th = (ushort*)take((size_t)256 * 512 * 2);
    ushort* W4th = (ushort*)take((size_t)512 * 256 * 2);
    ushort* W5th = (ushort*)take((size_t)256 * 64 * 2);

    // Buffer timeline (reads left, writes right; no overlap within a dispatch):
    //   L1g:  x        -> H1h (RA)       [fp16 out]
    //   agg1: H1h (RA) -> X1h (RB)       [fp16 in/out, bias+relu]
    //   agg2: X1h (RB) -> A2h (RC)       [fp16 in/out]
    //   L2 :  A2h (RC) -> X2h (RA)       [fp16 out, bias+relu]
    //   agg3: X2h (RA) -> A3h (RB)       [fp16 in/out]
    //   L3 :  A3h (RB) -> X3h (RC)       [fp16 out, bias+relu]
    //   L4 :  X3h (RC) -> H4h (RA)       [fp16 out]
    //   agg4: H4h (RA) -> X4h (RB)       [fp16 in/out, bias+relu]
    //   L5 :  X4h (RB) -> H5h (RA)       [fp16 out]
    //   agg5: H5h (RA) -> X5h (RB)       [fp16 in/out, bias+relu]
    //   L6 :  X5h (RB) -> H6f (RA)       [fp16 in, f32 out]
    //   agg6: H6f (RA) -> out            [f32]
    ushort* H1h = (ushort*)RA;                     // NN x 64 fp16
    ushort* X1h = (ushort*)RB;                     // NN x 64 fp16
    ushort* A2h = (ushort*)RC;                     // NN x 64 fp16
    ushort* X2h = (ushort*)RA;                     // NN x 256 fp16
    ushort* A3h = (ushort*)RB;                     // NN x 256 fp16
    ushort* X3h = (ushort*)RC;                     // NN x 512 fp16
    ushort* H4h = (ushort*)RA;                     // NN x 256 fp16
    ushort* X4h = (ushort*)RB;                     // NN x 256 fp16
    ushort* H5h = (ushort*)RA;                     // NN x 64 fp16
    ushort* X5h = (ushort*)RB;                     // NN x 64 fp16
    float* H6f = (float*)RA;                       // NN x 16 f32

    // CSR build (bucket sort; also produces row_ptr + dinv)
    zero_int_kernel<<<1, 256, 0, stream>>>(gcnt, 256);
    bucket_hist_kernel<<<EB_BLOCKS, 256, 0, stream>>>(e_dst, gcnt);
    bucket_scan_kernel<<<1, 256, 0, stream>>>(gcnt, bbase, bcur, row_ptr);
    edge_bin_kernel<<<EB_BLOCKS, 256, 0, stream>>>(e_src, e_dst, bcur, ebuf);
    bucket_sort_kernel<<<NBUK, 256, 0, stream>>>(bbase, ebuf, col_src, row_ptr, dinv);

    // fused weight splits (W2,W3,W4,W5) -> fp16 single plane
    split_all_kernel<<<(294912 + 255) / 256, 256, 0, stream>>>(
        W2, W3, W4, W5, W2th, W3th, W4th, W5th);

    const int aggGrid256 = (NN + 3) / 4;    // WD=256: 4 nodes/block
    const int aggGrid64v = (NN + 15) / 16;  // WD=64: 16 nodes/block
    const int aggGrid16v = (NN + 63) / 64;  // WD=16: 64 nodes/block
    const int mrows = (NN + 127) / 128;     // 391

    // L1 (GEMM-first): H1 = x@W1 (fp16 out) ; X1 = relu(S*H1+b1) (fp16)
    {
        dim3 g(1, (NN + 63) / 64);
        gemm_small_kernel<false, false, true><<<g, 256, 0, stream>>>(
            x, W1, nullptr, nullptr, H1h, NN, 35, 64);
    }
    aggregate_vec_kernel<64, true, true, true, true><<<aggGrid64v, 256, 0, stream>>>(
        (const float*)H1h, dinv, row_ptr, col_src, b1, nullptr, X1h);
    // L2: agg(X1,64) -> A2h fp16 ; X2 = relu(A2@W2+b2) -> X2h (256 fp16)
    aggregate_vec_kernel<64, false, false, true, true><<<aggGrid64v, 256, 0, stream>>>(
        (const float*)X1h, dinv, row_ptr, col_src, nullptr, nullptr, A2h);
    {
        dim3 g(2, mrows);
        gemm_f16_kernel<true, true><<<g, 256, 0, stream>>>(A2h, W2th, b2,
                                                           nullptr, X2h, NN, 64, 256);
    }
    // L3: agg(X2 fp16,256) -> A3h fp16 ; X3 = relu(A3@W3+b3) -> X3h (512 fp16)
    aggregate_vec_kernel<256, false, false, true, true><<<aggGrid256, 256, 0, stream>>>(
        (const float*)X2h, dinv, row_ptr, col_src, nullptr, nullptr, A3h);
    {
        dim3 g(4, mrows);
        gemm_f16_kernel<true, true><<<g, 256, 0, stream>>>(A3h, W3th, b3,
                                                           nullptr, X3h, NN, 256, 512);
    }
    // L4: H4 = X3@W4 -> H4h (256 fp16) ; X4 = relu(S*H4+b4) -> X4h (256 fp16)
    {
        dim3 g(2, mrows);
        gemm_f16_kernel<true, false><<<g, 256, 0, stream>>>(X3h, W4th, nullptr,
                                                            nullptr, H4h, NN, 512, 256);
    }
    aggregate_vec_kernel<256, true, true, true, true><<<aggGrid256, 256, 0, stream>>>(
        (const float*)H4h, dinv, row_ptr, col_src, b4, nullptr, X4h);
    // L5: H5 = X4@W5 -> H5h (64 fp16) ; X5 = relu(S*H5+b5) -> X5h (64 fp16)
    {
        dim3 g(1, mrows);
        gemm_f16_kernel<true, false><<<g, 256, 0, stream>>>(X4h, W5th, nullptr,
                                                            nullptr, H5h, NN, 256, 64);
    }
    aggregate_vec_kernel<64, true, true, true, true><<<aggGrid64v, 256, 0, stream>>>(
        (const float*)H5h, dinv, row_ptr, col_src, b5, nullptr, X5h);
    // L6: H6 = X5@W6 -> H6f (16 f32) ; out = S*H6 + b6
    {
        dim3 g(1, (NN + 63) / 64);
        gemm_small_kernel<false, true, false><<<g, 256, 0, stream>>>(
            (const float*)X5h, W6, nullptr, H6f, nullptr, NN, 64, 16);
    }
    aggregate_vec_kernel<16, true, false, false, false><<<aggGrid16v, 256, 0, stream>>>(
        H6f, dinv, row_ptr, col_src, b6, out, nullptr);
}